// Round 8
// baseline (53.156 us; speedup 1.0000x reference)
//
#include <hip/hip_runtime.h>
#include <math.h>

#define D 128
#define G 256

// ws layout:
//   [0,      512)           u  (128 f32) = Wp @ We[0:G]
//   [512,    516)           c  (scalar)  = bp . We[0:G]
//   [1024,   1024 + 4*B)    s[B]   per-graph gated sums
//   [65536,  65536 + 4*B)   pg[B]  hv[last_idx[g]] . we2

// DPP-based add of a permuted copy (VALU pipe, no LDS/DS traffic).
template <int CTRL>
__device__ __forceinline__ float dpp_add(float x) {
    int yi = __builtin_amdgcn_update_dpp(0, __float_as_int(x), CTRL, 0xf, 0xf, true);
    return x + __int_as_float(yi);
}

// Sum over each 16-lane row, result in every lane of the row.
__device__ __forceinline__ float row16_sum(float x) {
    x = dpp_add<0xB1>(x);    // quad_perm xor1
    x = dpp_add<0x4E>(x);    // quad_perm xor2
    x = dpp_add<0x124>(x);   // row rotate 4
    x = dpp_add<0x128>(x);   // row rotate 8
    return x;
}

// After row16_sum, ROW_BCAST15 (0x142) adds lane15 -> lanes16-31 and
// lane47 -> lanes48-63 (bound_ctrl zeroes rows 0,2). Result: lanes 16-31
// hold half0's 32-lane sum, lanes 48-63 hold half1's. Leader = li==16.
__device__ __forceinline__ float half32_sum_at16(float x) {
    x = row16_sum(x);
    x = dpp_add<0x142>(x);
    return x;
}

// One 64-lane wave per block, role by blockIdx.x:
//   [0,128)          : u[b] = Wp[b,:] . We[0:256]
//   128              : c = bp . We[0:256]
//   [129, 129+nzero) : zero s (float4 stores)
__global__ void prep_kernel(const float* __restrict__ Wp,
                            const float* __restrict__ bp,
                            const float* __restrict__ We,
                            float* __restrict__ u,
                            float* __restrict__ c,
                            float* __restrict__ s,
                            int B) {
    int b    = blockIdx.x;
    int lane = threadIdx.x;   // 0..63

    if (b < 129) {
        const float* row = (b < D) ? (Wp + (size_t)b * G) : bp;
        float4 rv = ((const float4*)row)[lane];
        float4 wv = ((const float4*)We)[lane];
        float p = rv.x * wv.x + rv.y * wv.y + rv.z * wv.z + rv.w * wv.w;
        #pragma unroll
        for (int m = 32; m >= 1; m >>= 1) p += __shfl_xor(p, m, 64);
        if (lane == 0) {
            if (b < D) u[b] = p;
            else       *c  = p;
        }
        return;
    }
    int idx4 = (b - 129) * 64 + lane;            // float4 index into s
    if (idx4 * 4 + 3 < B) ((float4*)s)[idx4] = make_float4(0.f, 0.f, 0.f, 0.f);
    else {
        for (int j = idx4 * 4; j < B; ++j) s[j] = 0.f;   // tail (no-op if B%4==0)
    }
}

// Exactly nblocks streaming blocks (8192 waves = one full residency round).
// Each 32-lane half-wave processes 2 node rows per iteration (unrolled,
// both float4 loads issued up front for MLP). seg_ids is sorted, so the
// leader lane (li==16 after ROW_BCAST15 reduce) keeps a running
// (segment, acc) and flushes one atomicAdd per segment change.
// After its streaming chunk, each half-wave gathers pg[g] = hv[last_idx].we2.
__global__ __launch_bounds__(256, 8)
void node_kernel(const float* __restrict__ hv,
                 const float* __restrict__ Wg,
                 const float* __restrict__ bg,
                 const int*   __restrict__ seg_ids,
                 const float* __restrict__ u,
                 const float* __restrict__ cptr,
                 const float* __restrict__ We,
                 const int*   __restrict__ last_idx,
                 float*       __restrict__ s,
                 float*       __restrict__ pg,
                 int N, int B, int chunk, int nwaves) {
    int tid  = blockIdx.x * blockDim.x + threadIdx.x;
    int wave = tid >> 6;
    int lane = threadIdx.x & 63;
    int half = lane >> 5;   // which row of the pair
    int li   = lane & 31;   // lane within half

    const float4* hv4 = (const float4*)hv;

    int start = wave * chunk;
    if (start < N) {
        int end = min(start + chunk, N);   // start,end multiples of 4 (chunk%4==0, N%4==0)

        float4 wg4 = ((const float4*)Wg)[li];   // constant per lane, hoisted
        float4 u4  = ((const float4*)u)[li];
        float  bgv = *bg;
        float  cv  = *cptr;

        int   cur = -1;
        float acc = 0.f;

        for (int r0 = start; r0 < end; r0 += 4) {
            int rowA = r0 + half;
            int rowB = r0 + 2 + half;
            // issue both loads before any compute
            float4 vA = hv4[(size_t)rowA * 32 + li];
            float4 vB = hv4[(size_t)rowB * 32 + li];
            int segA = seg_ids[rowA];
            int segB = seg_ids[rowB];

            float a1 = vA.x * wg4.x + vA.y * wg4.y + vA.z * wg4.z + vA.w * wg4.w;
            float a2 = vA.x * u4.x  + vA.y * u4.y  + vA.z * u4.z  + vA.w * u4.w;
            float b1 = vB.x * wg4.x + vB.y * wg4.y + vB.z * wg4.z + vB.w * wg4.w;
            float b2 = vB.x * u4.x  + vB.y * u4.y  + vB.z * u4.z  + vB.w * u4.w;
            a1 = half32_sum_at16(a1);
            a2 = half32_sum_at16(a2);
            b1 = half32_sum_at16(b1);
            b2 = half32_sum_at16(b2);
            float gateA = 1.f / (1.f + __expf(-(a1 + bgv)));
            float gateB = 1.f / (1.f + __expf(-(b1 + bgv)));
            float valA = gateA * (a2 + cv);
            float valB = gateB * (b2 + cv);
            if (li == 16) {
                if (segA != cur) {
                    if (cur >= 0) atomicAdd(&s[cur], acc);
                    cur = segA;
                    acc = valA;
                } else {
                    acc += valA;
                }
                if (segB != cur) {
                    atomicAdd(&s[cur], acc);   // cur >= 0 here (just set)
                    cur = segB;
                    acc = valB;
                } else {
                    acc += valB;
                }
            }
        }
        if (li == 16 && cur >= 0) atomicAdd(&s[cur], acc);
    }

    // gather tail: one graph per half-wave per pass
    float4 w24 = ((const float4*)We)[64 + li];   // we2 = We[256:384]
    int nhw = nwaves * 2;
    for (int g = wave * 2 + half; g < B; g += nhw) {
        int row = last_idx[g];
        float4 v = hv4[(size_t)row * 32 + li];
        float p = v.x * w24.x + v.y * w24.y + v.z * w24.z + v.w * w24.w;
        p = half32_sum_at16(p);
        if (li == 16) pg[g] = p;
    }
}

// One thread per graph: logit = s[g] + pg[g] + be, stable log-sigmoid + select.
__global__ void final_kernel(const float* __restrict__ s,
                             const float* __restrict__ pg,
                             const float* __restrict__ be,
                             const int*   __restrict__ a,
                             float*       __restrict__ out,
                             int B) {
    int g = blockIdx.x * blockDim.x + threadIdx.x;
    if (g >= B) return;
    float logit = s[g] + pg[g] + *be;
    float x = (a[g] != 0) ? logit : -logit;       // log_probs[:, a]
    // log_sigmoid(x) = min(x,0) - log1p(exp(-|x|))
    out[g] = fminf(x, 0.f) - log1pf(__expf(-fabsf(x)));
}

extern "C" void kernel_launch(void* const* d_in, const int* in_sizes, int n_in,
                              void* d_out, int out_size, void* d_ws, size_t ws_size,
                              hipStream_t stream) {
    const float* hv       = (const float*)d_in[0];
    const float* Wg       = (const float*)d_in[1];
    const float* bg       = (const float*)d_in[2];
    const float* Wp       = (const float*)d_in[3];
    const float* bp       = (const float*)d_in[4];
    const float* We       = (const float*)d_in[5];
    const float* be       = (const float*)d_in[6];
    const int*   seg_ids  = (const int*)d_in[7];
    const int*   last_idx = (const int*)d_in[8];
    const int*   a        = (const int*)d_in[9];
    float*       out      = (float*)d_out;

    int N = in_sizes[0] / D;
    int B = in_sizes[8];

    float* u  = (float*)d_ws;
    float* c  = (float*)((char*)d_ws + 512);
    float* s  = (float*)((char*)d_ws + 1024);
    float* pg = (float*)((char*)d_ws + 65536);

    // prep: 129 weight blocks + zero-s blocks
    int nzero = (B / 4 + 63) / 64;
    prep_kernel<<<129 + nzero, 64, 0, stream>>>(Wp, bp, We, u, c, s, B);

    // node: exactly one residency round (8 blocks/CU x 256 CU), gather folded
    const int nblocks = 2048;
    int nwaves = nblocks * 256 / 64;          // 8192
    int chunk = (N + nwaves - 1) / nwaves;
    chunk = (chunk + 3) & ~3;                 // multiple of 4: unroll-2 x 2 halves
    node_kernel<<<nblocks, 256, 0, stream>>>(
        hv, Wg, bg, seg_ids, u, c, We, last_idx, s, pg, N, B, chunk, nwaves);

    int fblocks = (B + 255) / 256;
    final_kernel<<<fblocks, 256, 0, stream>>>(s, pg, be, a, out, B);
}